// Round 1
// baseline (28410.941 us; speedup 1.0000x reference)
//
#include <hip/hip_runtime.h>
#include <math.h>

// Problem constants
#define T_STEPS 1024
#define BATCH   32
#define HID     512
#define G4      2048          // 4*HID
#define KDIM    1024          // I + H (concat [x|h])
#define NWG     128           // total workgroups (64 per layer)
#define WGL     64            // WGs per layer
#define JPW     8             // h-columns owned per WG
#define APAD    1032          // padded row stride (shorts) = 1024 + 8 (bank spread)

#define OUT_ELEMS   (BATCH * T_STEPS * HID)          // 16777216
#define H_OFF       OUT_ELEMS
#define C_OFF       (OUT_ELEMS + 2 * BATCH * HID)

typedef __attribute__((ext_vector_type(8))) short short8;
typedef __attribute__((ext_vector_type(4))) float f32x4;

__device__ __forceinline__ unsigned short f2bf(float f) {
    union { float f; unsigned u; } v; v.f = f;
    unsigned r = v.u + 0x7fffu + ((v.u >> 16) & 1u);   // RNE
    return (unsigned short)(r >> 16);
}

__device__ __forceinline__ float sigm(float x) { return 1.0f / (1.0f + __expf(-x)); }

// Flag-array grid barrier: WG i release-stores epoch to flags[i]; threads 0..NWG-1
// poll. No RMW contention. Requires all NWG blocks co-resident (1 WG/CU here,
// 128 blocks on 256 CUs).
__device__ __forceinline__ void gbar(unsigned* flags, int wg, unsigned epoch, int tid) {
    __threadfence();          // make this WG's global writes device-visible
    __syncthreads();
    if (tid == 0)
        __hip_atomic_store(&flags[wg], epoch, __ATOMIC_RELEASE, __HIP_MEMORY_SCOPE_AGENT);
    if (tid < NWG) {
        while (__hip_atomic_load(&flags[tid], __ATOMIC_ACQUIRE, __HIP_MEMORY_SCOPE_AGENT) < epoch)
            __builtin_amdgcn_s_sleep(2);
    }
    __syncthreads();
    __threadfence();          // read-side: invalidate L1 before consuming peers' h
}

__global__ void init_flags(unsigned* flags) {
    flags[threadIdx.x] = 0u;
}

__global__ void __launch_bounds__(256, 1)
lstm_persist(const float* __restrict__ x_in,   // [32][1024][512]
             const float* __restrict__ h0,     // [2][32][512]
             const float* __restrict__ c0,     // [2][32][512]
             const float* __restrict__ Wih,    // [2][2048][512]
             const float* __restrict__ Whh,    // [2][2048][512]
             const float* __restrict__ bih,    // [2][2048]
             const float* __restrict__ bhh,    // [2][2048]
             float* __restrict__ out,
             unsigned* __restrict__ flags,
             unsigned short* __restrict__ h1ring,  // [2][32][512] bf16
             unsigned short* __restrict__ h2ring)  // [2][32][512] bf16
{
    // LDS: A 66048B + W 66048B + gates 4096B + bias 128B = ~136.3 KB -> 1 WG/CU
    __shared__ short Abuf[BATCH * APAD];
    __shared__ short Wbuf[32 * APAD];
    __shared__ float gatebuf[BATCH][32];
    __shared__ float biasbuf[32];

    const int wg    = blockIdx.x;
    const int layer = (wg >= WGL) ? 1 : 0;
    const int wgl   = wg - layer * WGL;
    const int jbase = wgl * JPW;
    const int tid   = threadIdx.x;

    // ---- one-time: W slice -> LDS (bf16). 32 rows x 1024 (Wih|Whh). ----
    {
        const int lr  = tid >> 3;       // local gate row 0..31 (= g*8 + jloc)
        const int seg = tid & 7;        // 8 threads per row, 128 els each
        const int g = lr >> 3, jloc = lr & 7;
        const int r = g * HID + jbase + jloc;        // global gate row 0..2047
        const float* src = (seg < 4)
            ? (Wih + ((size_t)layer * G4 + r) * HID + seg * 128)
            : (Whh + ((size_t)layer * G4 + r) * HID + (seg - 4) * 128);
        short* dst = &Wbuf[lr * APAD + seg * 128];
        #pragma unroll 8
        for (int i = 0; i < 128; i += 4) {
            float4 v = *(const float4*)(src + i);
            short4 s4;
            s4.x = (short)f2bf(v.x); s4.y = (short)f2bf(v.y);
            s4.z = (short)f2bf(v.z); s4.w = (short)f2bf(v.w);
            *(short4*)(dst + i) = s4;
        }
    }
    if (tid < 32) {
        const int g = tid >> 3, jloc = tid & 7;
        const int r = g * HID + jbase + jloc;
        biasbuf[tid] = bih[(size_t)layer * G4 + r] + bhh[(size_t)layer * G4 + r];
    }

    // thread <-> (m = batch, jl = local h-col), stable across steps
    const int m  = tid >> 3;
    const int jl = tid & 7;
    const int jg = jbase + jl;

    float creg = c0[((size_t)layer * BATCH + m) * HID + jg];

    // init h rings: readers at step s use slot (s+1)&1.
    // layer0 step0 reads slot1 -> h0[0] in slot1.
    // layer1 first active step s=1 reads slot0 -> h0[1] in slot0 (and slot1, harmless).
    {
        unsigned short hb = f2bf(h0[((size_t)layer * BATCH + m) * HID + jg]);
        if (layer == 0) {
            h1ring[((size_t)1 * BATCH + m) * HID + jg] = hb;
        } else {
            h2ring[((size_t)0 * BATCH + m) * HID + jg] = hb;
            h2ring[((size_t)1 * BATCH + m) * HID + jg] = hb;
        }
    }

    gbar(flags, wg, 1u, tid);   // epoch 1: rings + W visible everywhere

    const int wv   = tid >> 6;          // wave 0..3
    const int lane = tid & 63;
    const int mi   = wv & 1;            // M-tile (batch 0-15 / 16-31)
    const int ni   = wv >> 1;           // N-tile (gate cols 0-15 / 16-31)
    const int n16  = lane & 15;
    const int quad = lane >> 4;

    const short* arow = &Abuf[(mi * 16 + n16) * APAD + quad * 8];
    const short* brow = &Wbuf[(ni * 16 + n16) * APAD + quad * 8];

    for (int s = 0; s <= T_STEPS; ++s) {
        const int t = (layer == 0) ? s : s - 1;
        const bool active = (t >= 0) && (t < T_STEPS);
        if (active) {
            const int rs = (s + 1) & 1;    // ring read slot (written at step s-1)
            const int b   = tid >> 3;      // A-build: 32 rows, 8 threads/row, 64 els
            const int seg = tid & 7;
            // x-part: cols 0..511
            if (layer == 0) {
                const float* src = x_in + ((size_t)b * T_STEPS + t) * HID + seg * 64;
                short* dst = &Abuf[b * APAD + seg * 64];
                #pragma unroll 4
                for (int i = 0; i < 64; i += 4) {
                    float4 v = *(const float4*)(src + i);
                    short4 s4;
                    s4.x = (short)f2bf(v.x); s4.y = (short)f2bf(v.y);
                    s4.z = (short)f2bf(v.z); s4.w = (short)f2bf(v.w);
                    *(short4*)(dst + i) = s4;
                }
            } else {
                const ushort4* src = (const ushort4*)(h1ring + ((size_t)rs * BATCH + b) * HID + seg * 64);
                ushort4* dst = (ushort4*)&Abuf[b * APAD + seg * 64];
                #pragma unroll 4
                for (int i = 0; i < 16; ++i) dst[i] = src[i];
            }
            // h-part: cols 512..1023 (own layer's recurrence)
            {
                const unsigned short* ring = (layer == 0) ? h1ring : h2ring;
                const ushort4* src = (const ushort4*)(ring + ((size_t)rs * BATCH + b) * HID + seg * 64);
                ushort4* dst = (ushort4*)&Abuf[b * APAD + 512 + seg * 64];
                #pragma unroll 4
                for (int i = 0; i < 16; ++i) dst[i] = src[i];
            }
            __syncthreads();

            // gates[32 batch][32 gate-cols] = A[32x1024] @ Wslice^T
            f32x4 acc = {0.f, 0.f, 0.f, 0.f};
            #pragma unroll 8
            for (int k0 = 0; k0 < KDIM; k0 += 32) {
                short8 af = *(const short8*)(arow + k0);
                short8 bf = *(const short8*)(brow + k0);
                acc = __builtin_amdgcn_mfma_f32_16x16x32_bf16(af, bf, acc, 0, 0, 0);
            }
            #pragma unroll
            for (int r = 0; r < 4; ++r)
                gatebuf[mi * 16 + quad * 4 + r][ni * 16 + n16] = acc[r];
            __syncthreads();

            // elementwise LSTM cell for (m, jl)
            float gi = gatebuf[m][0  + jl] + biasbuf[0  + jl];
            float gf = gatebuf[m][8  + jl] + biasbuf[8  + jl];
            float gg = gatebuf[m][16 + jl] + biasbuf[16 + jl];
            float go = gatebuf[m][24 + jl] + biasbuf[24 + jl];
            float iv = sigm(gi), fv = sigm(gf), gv = tanhf(gg), ov = sigm(go);
            creg = fv * creg + iv * gv;
            float hv = ov * tanhf(creg);

            const int wslot = s & 1;
            unsigned short* ringw = (layer == 0) ? h1ring : h2ring;
            ringw[((size_t)wslot * BATCH + m) * HID + jg] = f2bf(hv);
            if (layer == 1)
                out[((size_t)m * T_STEPS + t) * HID + jg] = hv;     // [B,T,H]
            if (t == T_STEPS - 1)
                out[H_OFF + ((size_t)layer * BATCH + m) * HID + jg] = hv;
        }
        if (s < T_STEPS)
            gbar(flags, wg, (unsigned)(s + 2), tid);
    }

    // final cell states
    out[C_OFF + ((size_t)layer * BATCH + m) * HID + jg] = creg;
}

extern "C" void kernel_launch(void* const* d_in, const int* in_sizes, int n_in,
                              void* d_out, int out_size, void* d_ws, size_t ws_size,
                              hipStream_t stream) {
    const float* x   = (const float*)d_in[0];
    const float* h0  = (const float*)d_in[1];
    const float* c0  = (const float*)d_in[2];
    const float* Wih = (const float*)d_in[3];
    const float* Whh = (const float*)d_in[4];
    const float* bih = (const float*)d_in[5];
    const float* bhh = (const float*)d_in[6];
    float* out = (float*)d_out;

    unsigned char* ws = (unsigned char*)d_ws;
    unsigned* flags = (unsigned*)ws;                                   // 128 uints
    unsigned short* h1ring = (unsigned short*)(ws + 1024);             // 64 KB
    unsigned short* h2ring = h1ring + 2 * BATCH * HID;                 // 64 KB

    hipLaunchKernelGGL(init_flags, dim3(1), dim3(NWG), 0, stream, flags);

    void* args[] = { (void*)&x, (void*)&h0, (void*)&c0, (void*)&Wih, (void*)&Whh,
                     (void*)&bih, (void*)&bhh, (void*)&out, (void*)&flags,
                     (void*)&h1ring, (void*)&h2ring };
    hipError_t e = hipLaunchCooperativeKernel((void*)lstm_persist, dim3(NWG), dim3(256),
                                              args, 0, stream);
    if (e != hipSuccess) {
        // Fallback: plain launch. 128 blocks @ 1 WG/CU on 256 CUs -> co-resident.
        hipLaunchKernelGGL(lstm_persist, dim3(NWG), dim3(256), 0, stream,
                           x, h0, c0, Wih, Whh, bih, bhh, out, flags, h1ring, h2ring);
    }
}

// Round 2
// 9594.761 us; speedup vs baseline: 2.9611x; 2.9611x over previous
//
#include <hip/hip_runtime.h>
#include <math.h>

// Problem constants
#define T_STEPS 1024
#define BATCH   32
#define HID     512
#define G4      2048          // 4*HID
#define KDIM    1024          // I + H (concat [x|h])
#define NWG     128           // total workgroups (64 per layer)
#define WGL     64            // WGs per layer
#define JPW     8             // h-columns owned per WG
#define APAD    1032          // padded row stride (shorts) = 129 16B-granules (odd)

#define OUT_ELEMS   (BATCH * T_STEPS * HID)          // 16777216
#define H_OFF       OUT_ELEMS
#define C_OFF       (OUT_ELEMS + 2 * BATCH * HID)

typedef __attribute__((ext_vector_type(8))) short short8;
typedef __attribute__((ext_vector_type(4))) float f32x4;
typedef __attribute__((ext_vector_type(2))) unsigned long long u64x2;

__device__ __forceinline__ unsigned short f2bf(float f) {
    union { float f; unsigned u; } v; v.f = f;
    unsigned r = v.u + 0x7fffu + ((v.u >> 16) & 1u);   // RNE
    return (unsigned short)(r >> 16);
}

__device__ __forceinline__ float sigm(float x) { return 1.0f / (1.0f + __expf(-x)); }

// Fence-free grid barrier. All cross-WG data moves via agent-scope relaxed
// atomics (sc1 -> LLC, bypassing the non-coherent per-XCD L2s), so no
// acquire/release fences (= L2 writeback/invalidate) are needed anywhere.
// Ordering: per-wave s_waitcnt vmcnt(0) drains the sc1 data stores to the
// coherence point; __syncthreads covers all waves; then publish the flag.
__device__ __forceinline__ void gbar(unsigned* flags, int wg, unsigned epoch, int tid) {
    asm volatile("s_waitcnt vmcnt(0)" ::: "memory");
    __syncthreads();
    if (tid == 0)
        __hip_atomic_store(&flags[wg], epoch, __ATOMIC_RELAXED, __HIP_MEMORY_SCOPE_AGENT);
    if (tid < NWG) {
        while (__hip_atomic_load(&flags[tid], __ATOMIC_RELAXED, __HIP_MEMORY_SCOPE_AGENT) < epoch)
            __builtin_amdgcn_s_sleep(1);
    }
    __syncthreads();
}

__global__ void init_flags(unsigned* flags) {
    flags[threadIdx.x] = 0u;
}

__global__ void __launch_bounds__(256, 1)
lstm_persist(const float* __restrict__ x_in,   // [32][1024][512]
             const float* __restrict__ h0,     // [2][32][512]
             const float* __restrict__ c0,     // [2][32][512]
             const float* __restrict__ Wih,    // [2][2048][512]
             const float* __restrict__ Whh,    // [2][2048][512]
             const float* __restrict__ bih,    // [2][2048]
             const float* __restrict__ bhh,    // [2][2048]
             float* __restrict__ out,
             unsigned* __restrict__ flags,
             unsigned short* __restrict__ h1ring,  // [2][32][512] bf16 (ws)
             unsigned short* __restrict__ h2ring,  // [2][32][512] bf16 (ws)
             unsigned short* __restrict__ xbf,     // [32][1024][512] bf16 (ws), optional
             int use_xbf)
{
    // LDS: A 66048B + W 66048B + gates 4224B + bias 128B ≈ 133 KB -> 1 WG/CU
    __shared__ __attribute__((aligned(16))) short Abuf[BATCH * APAD];
    __shared__ __attribute__((aligned(16))) short Wbuf[32 * APAD];
    __shared__ float gatebuf[BATCH][33];      // pad 33: conflict-free acc writes
    __shared__ float biasbuf[32];

    const int wg    = blockIdx.x;
    const int layer = (wg >= WGL) ? 1 : 0;
    const int wgl   = wg - layer * WGL;
    const int jbase = wgl * JPW;
    const int tid   = threadIdx.x;

    // ---- one-time: pre-convert x -> bf16 in ws (sc1 stores; read later via sc1) ----
    if (use_xbf) {
        const size_t total4 = (size_t)BATCH * T_STEPS * HID / 4;
        unsigned long long* dst = (unsigned long long*)xbf;
        for (size_t idx = (size_t)wg * 256 + tid; idx < total4; idx += (size_t)NWG * 256) {
            float4 v = *(const float4*)(x_in + idx * 4);
            unsigned long long pk = (unsigned long long)f2bf(v.x)
                                  | ((unsigned long long)f2bf(v.y) << 16)
                                  | ((unsigned long long)f2bf(v.z) << 32)
                                  | ((unsigned long long)f2bf(v.w) << 48);
            __hip_atomic_store(dst + idx, pk, __ATOMIC_RELAXED, __HIP_MEMORY_SCOPE_AGENT);
        }
    }

    // ---- one-time: W slice -> LDS (bf16), contiguous b128 writes ----
    {
        const int lr = tid >> 3;        // local gate row 0..31 (= gate*8 + jloc)
        const int g0 = tid & 7;
        const int gg = lr >> 3, jloc = lr & 7;
        const int r  = gg * HID + jbase + jloc;      // global gate row
        const float* srcA = Wih + ((size_t)layer * G4 + r) * HID;
        const float* srcB = Whh + ((size_t)layer * G4 + r) * HID;
        short* dstrow = &Wbuf[lr * APAD];
        #pragma unroll
        for (int i = 0; i < 16; ++i) {
            int g = g0 + 8 * i;         // 16B granule 0..127 within the 1024-col row
            const float* src = (g < 64) ? (srcA + g * 8) : (srcB + (g - 64) * 8);
            float4 v0 = *(const float4*)(src);
            float4 v1 = *(const float4*)(src + 4);
            short8 p;
            p[0] = (short)f2bf(v0.x); p[1] = (short)f2bf(v0.y);
            p[2] = (short)f2bf(v0.z); p[3] = (short)f2bf(v0.w);
            p[4] = (short)f2bf(v1.x); p[5] = (short)f2bf(v1.y);
            p[6] = (short)f2bf(v1.z); p[7] = (short)f2bf(v1.w);
            *(short8*)(dstrow + g * 8) = p;
        }
    }
    if (tid < 32) {
        const int g = tid >> 3, jloc = tid & 7;
        const int r = g * HID + jbase + jloc;
        biasbuf[tid] = bih[(size_t)layer * G4 + r] + bhh[(size_t)layer * G4 + r];
    }

    // thread <-> (m = batch, jl = local h-col), stable across steps
    const int m  = tid >> 3;
    const int jl = tid & 7;
    const int jg = jbase + jl;

    float creg = c0[((size_t)layer * BATCH + m) * HID + jg];

    // init h rings (sc1 u32 stores): readers at step s use slot (s+1)&1.
    {
        unsigned hb = (unsigned)f2bf(h0[((size_t)layer * BATCH + m) * HID + jg]);
        unsigned ob = __shfl_xor(hb, 1);
        if ((tid & 1) == 0) {
            unsigned val = hb | (ob << 16);
            unsigned short* ring = (layer == 0) ? h1ring : h2ring;
            if (layer == 0) {
                unsigned* p = (unsigned*)(ring + ((size_t)1 * BATCH + m) * HID + (jg & ~1));
                __hip_atomic_store(p, val, __ATOMIC_RELAXED, __HIP_MEMORY_SCOPE_AGENT);
            } else {
                unsigned* p0 = (unsigned*)(ring + ((size_t)0 * BATCH + m) * HID + (jg & ~1));
                unsigned* p1 = (unsigned*)(ring + ((size_t)1 * BATCH + m) * HID + (jg & ~1));
                __hip_atomic_store(p0, val, __ATOMIC_RELAXED, __HIP_MEMORY_SCOPE_AGENT);
                __hip_atomic_store(p1, val, __ATOMIC_RELAXED, __HIP_MEMORY_SCOPE_AGENT);
            }
        }
    }

    gbar(flags, wg, 1u, tid);   // epoch 1: rings + xbf at LLC everywhere

    const int wv   = tid >> 6;          // wave 0..3
    const int lane = tid & 63;
    const int mi   = wv & 1;            // M-tile (batch 0-15 / 16-31)
    const int ni   = wv >> 1;           // N-tile (gate cols 0-15 / 16-31)
    const int n16  = lane & 15;
    const int quad = lane >> 4;

    const short* arow = &Abuf[(mi * 16 + n16) * APAD + quad * 8];
    const short* brow = &Wbuf[(ni * 16 + n16) * APAD + quad * 8];

    const int b  = tid >> 3;            // A-build: row, 8 threads/row
    const int g0 = tid & 7;             // starting 16B granule

    for (int s = 0; s <= T_STEPS; ++s) {
        const int t = (layer == 0) ? s : s - 1;
        const bool active = (t >= 0) && (t < T_STEPS);
        if (active) {
            const int rs = (s + 1) & 1;    // ring read slot (written at step s-1)
            short* dstrow = &Abuf[b * APAD];

            // x-part: cols 0..511 (64 granules)
            if (layer == 0) {
                if (use_xbf) {
                    const unsigned long long* src =
                        (const unsigned long long*)(xbf + ((size_t)b * T_STEPS + t) * HID);
                    #pragma unroll
                    for (int i = 0; i < 8; ++i) {
                        int g = g0 + 8 * i;
                        u64x2 u;
                        u[0] = __hip_atomic_load(src + g * 2,     __ATOMIC_RELAXED, __HIP_MEMORY_SCOPE_AGENT);
                        u[1] = __hip_atomic_load(src + g * 2 + 1, __ATOMIC_RELAXED, __HIP_MEMORY_SCOPE_AGENT);
                        *(u64x2*)(dstrow + g * 8) = u;
                    }
                } else {
                    const float* src = x_in + ((size_t)b * T_STEPS + t) * HID;
                    #pragma unroll
                    for (int i = 0; i < 8; ++i) {
                        int g = g0 + 8 * i;
                        float4 v0 = *(const float4*)(src + g * 8);
                        float4 v1 = *(const float4*)(src + g * 8 + 4);
                        short8 p;
                        p[0] = (short)f2bf(v0.x); p[1] = (short)f2bf(v0.y);
                        p[2] = (short)f2bf(v0.z); p[3] = (short)f2bf(v0.w);
                        p[4] = (short)f2bf(v1.x); p[5] = (short)f2bf(v1.y);
                        p[6] = (short)f2bf(v1.z); p[7] = (short)f2bf(v1.w);
                        *(short8*)(dstrow + g * 8) = p;
                    }
                }
            } else {
                const unsigned long long* src =
                    (const unsigned long long*)(h1ring + ((size_t)rs * BATCH + b) * HID);
                #pragma unroll
                for (int i = 0; i < 8; ++i) {
                    int g = g0 + 8 * i;
                    u64x2 u;
                    u[0] = __hip_atomic_load(src + g * 2,     __ATOMIC_RELAXED, __HIP_MEMORY_SCOPE_AGENT);
                    u[1] = __hip_atomic_load(src + g * 2 + 1, __ATOMIC_RELAXED, __HIP_MEMORY_SCOPE_AGENT);
                    *(u64x2*)(dstrow + g * 8) = u;
                }
            }
            // h-part: cols 512..1023 (own layer's recurrence)
            {
                const unsigned short* ring = (layer == 0) ? h1ring : h2ring;
                const unsigned long long* src =
                    (const unsigned long long*)(ring + ((size_t)rs * BATCH + b) * HID);
                #pragma unroll
                for (int i = 0; i < 8; ++i) {
                    int g = g0 + 8 * i;
                    u64x2 u;
                    u[0] = __hip_atomic_load(src + g * 2,     __ATOMIC_RELAXED, __HIP_MEMORY_SCOPE_AGENT);
                    u[1] = __hip_atomic_load(src + g * 2 + 1, __ATOMIC_RELAXED, __HIP_MEMORY_SCOPE_AGENT);
                    *(u64x2*)(dstrow + 512 + g * 8) = u;
                }
            }
            __syncthreads();

            // gates[32 batch][32 gate-cols] = A[32x1024] @ Wslice^T
            f32x4 acc = {0.f, 0.f, 0.f, 0.f};
            #pragma unroll 16
            for (int k0 = 0; k0 < KDIM; k0 += 32) {
                short8 af = *(const short8*)(arow + k0);
                short8 bf = *(const short8*)(brow + k0);
                acc = __builtin_amdgcn_mfma_f32_16x16x32_bf16(af, bf, acc, 0, 0, 0);
            }
            #pragma unroll
            for (int r = 0; r < 4; ++r)
                gatebuf[mi * 16 + quad * 4 + r][ni * 16 + n16] = acc[r];
            __syncthreads();

            // elementwise LSTM cell for (m, jl)
            float gi = gatebuf[m][0  + jl] + biasbuf[0  + jl];
            float gf = gatebuf[m][8  + jl] + biasbuf[8  + jl];
            float gg = gatebuf[m][16 + jl] + biasbuf[16 + jl];
            float go = gatebuf[m][24 + jl] + biasbuf[24 + jl];
            float iv = sigm(gi), fv = sigm(gf), gv = tanhf(gg), ov = sigm(go);
            creg = fv * creg + iv * gv;
            float hv = ov * tanhf(creg);

            // publish h (sc1 u32 store, lane-paired)
            {
                const int wslot = s & 1;
                unsigned hb = (unsigned)f2bf(hv);
                unsigned ob = __shfl_xor(hb, 1);
                if ((tid & 1) == 0) {
                    unsigned val = hb | (ob << 16);
                    unsigned short* ringw = (layer == 0) ? h1ring : h2ring;
                    unsigned* p = (unsigned*)(ringw + ((size_t)wslot * BATCH + m) * HID + (jg & ~1));
                    __hip_atomic_store(p, val, __ATOMIC_RELAXED, __HIP_MEMORY_SCOPE_AGENT);
                }
            }
            if (layer == 1)
                out[((size_t)m * T_STEPS + t) * HID + jg] = hv;     // [B,T,H]
            if (t == T_STEPS - 1)
                out[H_OFF + ((size_t)layer * BATCH + m) * HID + jg] = hv;
        }
        if (s < T_STEPS)
            gbar(flags, wg, (unsigned)(s + 2), tid);
    }

    // final cell states
    out[C_OFF + ((size_t)layer * BATCH + m) * HID + jg] = creg;
}

extern "C" void kernel_launch(void* const* d_in, const int* in_sizes, int n_in,
                              void* d_out, int out_size, void* d_ws, size_t ws_size,
                              hipStream_t stream) {
    const float* x   = (const float*)d_in[0];
    const float* h0  = (const float*)d_in[1];
    const float* c0  = (const float*)d_in[2];
    const float* Wih = (const float*)d_in[3];
    const float* Whh = (const float*)d_in[4];
    const float* bih = (const float*)d_in[5];
    const float* bhh = (const float*)d_in[6];
    float* out = (float*)d_out;

    unsigned char* ws = (unsigned char*)d_ws;
    unsigned* flags = (unsigned*)ws;                                   // 128 uints
    unsigned short* h1ring = (unsigned short*)(ws + 1024);             // 64 KB
    unsigned short* h2ring = h1ring + 2 * BATCH * HID;                 // 64 KB
    unsigned short* xbf    = h2ring + 2 * BATCH * HID;                 // 32 MB (optional)

    const size_t xbf_need = 1024 + 2 * 128 * 1024 +
                            (size_t)BATCH * T_STEPS * HID * 2 + 4096;
    int use_xbf = (ws_size >= xbf_need) ? 1 : 0;

    hipLaunchKernelGGL(init_flags, dim3(1), dim3(NWG), 0, stream, flags);

    void* args[] = { (void*)&x, (void*)&h0, (void*)&c0, (void*)&Wih, (void*)&Whh,
                     (void*)&bih, (void*)&bhh, (void*)&out, (void*)&flags,
                     (void*)&h1ring, (void*)&h2ring, (void*)&xbf, (void*)&use_xbf };
    hipError_t e = hipLaunchCooperativeKernel((void*)lstm_persist, dim3(NWG), dim3(256),
                                              args, 0, stream);
    if (e != hipSuccess) {
        // Fallback: plain launch. 128 blocks @ 1 WG/CU on 256 CUs -> co-resident.
        hipLaunchKernelGGL(lstm_persist, dim3(NWG), dim3(256), 0, stream,
                           x, h0, c0, Wih, Whh, bih, bhh, out, flags,
                           h1ring, h2ring, xbf, use_xbf);
    }
}

// Round 3
// 8725.915 us; speedup vs baseline: 3.2559x; 1.0996x over previous
//
#include <hip/hip_runtime.h>
#include <math.h>

// Problem constants
#define T_STEPS 1024
#define BATCH   32
#define HID     512
#define G4      2048          // 4*HID
#define KDIM    1024          // I + H (concat [x|h])
#define NWG     128           // total workgroups (64 per layer)
#define WGL     64            // WGs per layer
#define JPW     8             // h-columns owned per WG
#define APAD    1032          // padded row stride (shorts)

#define OUT_ELEMS   (BATCH * T_STEPS * HID)          // 16777216
#define H_OFF       OUT_ELEMS
#define C_OFF       (OUT_ELEMS + 2 * BATCH * HID)

typedef __attribute__((ext_vector_type(8))) short short8;
typedef __attribute__((ext_vector_type(4))) float f32x4;
typedef __attribute__((ext_vector_type(2))) unsigned long long u64x2;

__device__ __forceinline__ unsigned short f2bf(float f) {
    union { float f; unsigned u; } v; v.f = f;
    unsigned r = v.u + 0x7fffu + ((v.u >> 16) & 1u);   // RNE
    return (unsigned short)(r >> 16);
}

__device__ __forceinline__ float sigm(float x)  { return 1.0f / (1.0f + __expf(-x)); }
__device__ __forceinline__ float ftanh(float x) { return 1.0f - 2.0f / (__expf(2.0f * x) + 1.0f); }

// ---- two-level aggregated grid barrier (fence-free: all cross-WG data is sc1) ----
// arrive: drain this WG's sc1 data stores, then post per-WG flag (agent atomic).
// wait:   WG0 aggregates 128 flags (sole poll set), posts one release word;
//         every other WG polls the release word with ONE thread.
__device__ __forceinline__ void g_arrive(unsigned* flags, int wg, unsigned epoch, int tid) {
    asm volatile("s_waitcnt vmcnt(0)" ::: "memory");
    __syncthreads();
    if (tid == 0)
        __hip_atomic_store(&flags[wg], epoch, __ATOMIC_RELAXED, __HIP_MEMORY_SCOPE_AGENT);
}

__device__ __forceinline__ void g_wait(unsigned* flags, unsigned* rel, int wg, unsigned epoch, int tid) {
    if (wg == 0) {
        if (tid < NWG) {
            while (__hip_atomic_load(&flags[tid], __ATOMIC_RELAXED, __HIP_MEMORY_SCOPE_AGENT) < epoch)
                __builtin_amdgcn_s_sleep(1);
        }
        __syncthreads();
        if (tid == 0)
            __hip_atomic_store(rel, epoch, __ATOMIC_RELAXED, __HIP_MEMORY_SCOPE_AGENT);
    } else {
        if (tid == 0) {
            while (__hip_atomic_load(rel, __ATOMIC_RELAXED, __HIP_MEMORY_SCOPE_AGENT) < epoch)
                __builtin_amdgcn_s_sleep(2);
        }
        __syncthreads();
    }
}

__global__ void init_flags(unsigned* flags) {
    flags[threadIdx.x] = 0u;     // 256 entries: 128 arrival flags + release word + spare
}

__global__ void __launch_bounds__(256, 1)
lstm_persist(const float* __restrict__ x_in,   // [32][1024][512]
             const float* __restrict__ h0,     // [2][32][512]
             const float* __restrict__ c0,     // [2][32][512]
             const float* __restrict__ Wih,    // [2][2048][512]
             const float* __restrict__ Whh,    // [2][2048][512]
             const float* __restrict__ bih,    // [2][2048]
             const float* __restrict__ bhh,    // [2][2048]
             float* __restrict__ out,
             unsigned* __restrict__ flags,
             unsigned short* __restrict__ h1ring,  // [2][32][512] bf16 (ws, sc1)
             unsigned short* __restrict__ h2ring,  // [2][32][512] bf16 (ws, sc1)
             unsigned short* __restrict__ xbf,     // [32][1024][512] bf16 (ws, plain)
             int use_xbf)
{
    __shared__ __attribute__((aligned(16))) short Abuf[BATCH * APAD];
    __shared__ __attribute__((aligned(16))) short Wbuf[32 * APAD];
    __shared__ float gatebuf[BATCH][33];
    __shared__ float biasbuf[32];

    const int wg    = blockIdx.x;
    const int layer = (wg >= WGL) ? 1 : 0;
    const int wgl   = wg - layer * WGL;
    const int jbase = wgl * JPW;
    const int tid   = threadIdx.x;
    unsigned* rel   = flags + NWG;

    // ---- one-time: pre-convert x -> bf16 in ws (plain stores + release fence) ----
    if (use_xbf) {
        const size_t total4 = (size_t)BATCH * T_STEPS * HID / 4;
        unsigned long long* dst = (unsigned long long*)xbf;
        for (size_t idx = (size_t)wg * 256 + tid; idx < total4; idx += (size_t)NWG * 256) {
            float4 v = *(const float4*)(x_in + idx * 4);
            unsigned long long pk = (unsigned long long)f2bf(v.x)
                                  | ((unsigned long long)f2bf(v.y) << 16)
                                  | ((unsigned long long)f2bf(v.z) << 32)
                                  | ((unsigned long long)f2bf(v.w) << 48);
            dst[idx] = pk;
        }
        __builtin_amdgcn_fence(__ATOMIC_RELEASE, "agent");   // writeback L2 -> visible
    }

    // ---- one-time: W slice -> LDS (bf16) ----
    {
        const int lr = tid >> 3;        // local gate row 0..31 (= gate*8 + jloc)
        const int g0 = tid & 7;
        const int gg = lr >> 3, jloc = lr & 7;
        const int r  = gg * HID + jbase + jloc;      // global gate row
        const float* srcA = Wih + ((size_t)layer * G4 + r) * HID;
        const float* srcB = Whh + ((size_t)layer * G4 + r) * HID;
        short* dstrow = &Wbuf[lr * APAD];
        #pragma unroll
        for (int i = 0; i < 16; ++i) {
            int g = g0 + 8 * i;         // 16B granule 0..127
            const float* src = (g < 64) ? (srcA + g * 8) : (srcB + (g - 64) * 8);
            float4 v0 = *(const float4*)(src);
            float4 v1 = *(const float4*)(src + 4);
            short8 p;
            p[0] = (short)f2bf(v0.x); p[1] = (short)f2bf(v0.y);
            p[2] = (short)f2bf(v0.z); p[3] = (short)f2bf(v0.w);
            p[4] = (short)f2bf(v1.x); p[5] = (short)f2bf(v1.y);
            p[6] = (short)f2bf(v1.z); p[7] = (short)f2bf(v1.w);
            *(short8*)(dstrow + g * 8) = p;
        }
    }
    if (tid < 32) {
        const int g = tid >> 3, jloc = tid & 7;
        const int r = g * HID + jbase + jloc;
        biasbuf[tid] = bih[(size_t)layer * G4 + r] + bhh[(size_t)layer * G4 + r];
    }

    const int m  = tid >> 3;
    const int jl = tid & 7;
    const int jg = jbase + jl;

    float creg = c0[((size_t)layer * BATCH + m) * HID + jg];

    // init h rings (sc1): readers at step s use slot (s+1)&1
    {
        unsigned hb = (unsigned)f2bf(h0[((size_t)layer * BATCH + m) * HID + jg]);
        unsigned ob = __shfl_xor(hb, 1);
        if ((tid & 1) == 0) {
            unsigned val = hb | (ob << 16);
            unsigned short* ring = (layer == 0) ? h1ring : h2ring;
            if (layer == 0) {
                unsigned* p = (unsigned*)(ring + ((size_t)1 * BATCH + m) * HID + (jg & ~1));
                __hip_atomic_store(p, val, __ATOMIC_RELAXED, __HIP_MEMORY_SCOPE_AGENT);
            } else {
                unsigned* p0 = (unsigned*)(ring + ((size_t)0 * BATCH + m) * HID + (jg & ~1));
                unsigned* p1 = (unsigned*)(ring + ((size_t)1 * BATCH + m) * HID + (jg & ~1));
                __hip_atomic_store(p0, val, __ATOMIC_RELAXED, __HIP_MEMORY_SCOPE_AGENT);
                __hip_atomic_store(p1, val, __ATOMIC_RELAXED, __HIP_MEMORY_SCOPE_AGENT);
            }
        }
    }

    g_arrive(flags, wg, 1u, tid);
    g_wait(flags, rel, wg, 1u, tid);
    __builtin_amdgcn_fence(__ATOMIC_ACQUIRE, "agent");   // invalidate: xbf plain-readable

    const int wv   = tid >> 6;
    const int lane = tid & 63;
    const int mi   = wv & 1;
    const int ni   = wv >> 1;
    const int n16  = lane & 15;
    const int quad = lane >> 4;

    const short* arow = &Abuf[(mi * 16 + n16) * APAD + quad * 8];
    const short* brow = &Wbuf[(ni * 16 + n16) * APAD + quad * 8];

    const int b  = tid >> 3;            // A-build: row, 8 threads/row
    const int g0 = tid & 7;             // starting 16B granule

    for (int s = 0; s <= T_STEPS; ++s) {
        const int t = (layer == 0) ? s : s - 1;
        const bool active = (t >= 0) && (t < T_STEPS);
        float hv = 0.0f;
        if (active) {
            const int rs = (s + 1) & 1;
            short* dstrow = &Abuf[b * APAD];

            if (layer == 0) {
                if (s == 0) {   // x(t=0): not prebuilt yet (plain L2 loads)
                    if (use_xbf) {
                        const unsigned long long* src =
                            (const unsigned long long*)(xbf + ((size_t)b * T_STEPS) * HID);
                        #pragma unroll
                        for (int i = 0; i < 8; ++i) {
                            int g = g0 + 8 * i;
                            *(u64x2*)(dstrow + g * 8) = *(const u64x2*)(src + g * 2);
                        }
                    } else {
                        const float* src = x_in + ((size_t)b * T_STEPS) * HID;
                        #pragma unroll
                        for (int i = 0; i < 8; ++i) {
                            int g = g0 + 8 * i;
                            float4 v0 = *(const float4*)(src + g * 8);
                            float4 v1 = *(const float4*)(src + g * 8 + 4);
                            short8 p;
                            p[0] = (short)f2bf(v0.x); p[1] = (short)f2bf(v0.y);
                            p[2] = (short)f2bf(v0.z); p[3] = (short)f2bf(v0.w);
                            p[4] = (short)f2bf(v1.x); p[5] = (short)f2bf(v1.y);
                            p[6] = (short)f2bf(v1.z); p[7] = (short)f2bf(v1.w);
                            *(short8*)(dstrow + g * 8) = p;
                        }
                    }
                }
            } else {
                // x-part = h1(t) (sc1 LLC loads)
                const unsigned long long* src =
                    (const unsigned long long*)(h1ring + ((size_t)rs * BATCH + b) * HID);
                #pragma unroll
                for (int i = 0; i < 8; ++i) {
                    int g = g0 + 8 * i;
                    u64x2 u;
                    u[0] = __hip_atomic_load(src + g * 2,     __ATOMIC_RELAXED, __HIP_MEMORY_SCOPE_AGENT);
                    u[1] = __hip_atomic_load(src + g * 2 + 1, __ATOMIC_RELAXED, __HIP_MEMORY_SCOPE_AGENT);
                    *(u64x2*)(dstrow + g * 8) = u;
                }
            }
            // h-part: cols 512..1023, own layer's recurrence (sc1)
            {
                const unsigned short* ring = (layer == 0) ? h1ring : h2ring;
                const unsigned long long* src =
                    (const unsigned long long*)(ring + ((size_t)rs * BATCH + b) * HID);
                #pragma unroll
                for (int i = 0; i < 8; ++i) {
                    int g = g0 + 8 * i;
                    u64x2 u;
                    u[0] = __hip_atomic_load(src + g * 2,     __ATOMIC_RELAXED, __HIP_MEMORY_SCOPE_AGENT);
                    u[1] = __hip_atomic_load(src + g * 2 + 1, __ATOMIC_RELAXED, __HIP_MEMORY_SCOPE_AGENT);
                    *(u64x2*)(dstrow + 512 + g * 8) = u;
                }
            }
            __syncthreads();

            f32x4 acc = {0.f, 0.f, 0.f, 0.f};
            #pragma unroll 16
            for (int k0 = 0; k0 < KDIM; k0 += 32) {
                short8 af = *(const short8*)(arow + k0);
                short8 bf = *(const short8*)(brow + k0);
                acc = __builtin_amdgcn_mfma_f32_16x16x32_bf16(af, bf, acc, 0, 0, 0);
            }
            #pragma unroll
            for (int r = 0; r < 4; ++r)
                gatebuf[mi * 16 + quad * 4 + r][ni * 16 + n16] = acc[r];
            __syncthreads();

            float gi = gatebuf[m][0  + jl] + biasbuf[0  + jl];
            float gf = gatebuf[m][8  + jl] + biasbuf[8  + jl];
            float gg = gatebuf[m][16 + jl] + biasbuf[16 + jl];
            float go = gatebuf[m][24 + jl] + biasbuf[24 + jl];
            float iv = sigm(gi), fv = sigm(gf), gv = ftanh(gg), ov = sigm(go);
            creg = fv * creg + iv * gv;
            hv = ov * ftanh(creg);

            // publish h (sc1, lane-paired u32)
            {
                const int wslot = s & 1;
                unsigned hb = (unsigned)f2bf(hv);
                unsigned ob = __shfl_xor(hb, 1);
                if ((tid & 1) == 0) {
                    unsigned val = hb | (ob << 16);
                    unsigned short* ringw = (layer == 0) ? h1ring : h2ring;
                    unsigned* p = (unsigned*)(ringw + ((size_t)wslot * BATCH + m) * HID + (jg & ~1));
                    __hip_atomic_store(p, val, __ATOMIC_RELAXED, __HIP_MEMORY_SCOPE_AGENT);
                }
            }
            if (t == T_STEPS - 1)
                out[H_OFF + ((size_t)layer * BATCH + m) * HID + jg] = hv;
        }

        const bool last = (s == T_STEPS);
        if (!last) g_arrive(flags, wg, (unsigned)(s + 2), tid);

        // ---- wait-window work (off the critical sync path) ----
        if (active && layer == 1)
            out[((size_t)m * T_STEPS + t) * HID + jg] = hv;     // [B,T,H], plain store
        if (active && layer == 0 && t + 1 < T_STEPS) {
            // prebuild next step's x-part of A (plain L2 loads; Abuf free: MFMA done)
            short* dstrow = &Abuf[b * APAD];
            if (use_xbf) {
                const unsigned long long* src =
                    (const unsigned long long*)(xbf + ((size_t)b * T_STEPS + (t + 1)) * HID);
                #pragma unroll
                for (int i = 0; i < 8; ++i) {
                    int g = g0 + 8 * i;
                    *(u64x2*)(dstrow + g * 8) = *(const u64x2*)(src + g * 2);
                }
            } else {
                const float* src = x_in + ((size_t)b * T_STEPS + (t + 1)) * HID;
                #pragma unroll
                for (int i = 0; i < 8; ++i) {
                    int g = g0 + 8 * i;
                    float4 v0 = *(const float4*)(src + g * 8);
                    float4 v1 = *(const float4*)(src + g * 8 + 4);
                    short8 p;
                    p[0] = (short)f2bf(v0.x); p[1] = (short)f2bf(v0.y);
                    p[2] = (short)f2bf(v0.z); p[3] = (short)f2bf(v0.w);
                    p[4] = (short)f2bf(v1.x); p[5] = (short)f2bf(v1.y);
                    p[6] = (short)f2bf(v1.z); p[7] = (short)f2bf(v1.w);
                    *(short8*)(dstrow + g * 8) = p;
                }
            }
        }
        if (!last) g_wait(flags, rel, wg, (unsigned)(s + 2), tid);
    }

    out[C_OFF + ((size_t)layer * BATCH + m) * HID + jg] = creg;
}

extern "C" void kernel_launch(void* const* d_in, const int* in_sizes, int n_in,
                              void* d_out, int out_size, void* d_ws, size_t ws_size,
                              hipStream_t stream) {
    const float* x   = (const float*)d_in[0];
    const float* h0  = (const float*)d_in[1];
    const float* c0  = (const float*)d_in[2];
    const float* Wih = (const float*)d_in[3];
    const float* Whh = (const float*)d_in[4];
    const float* bih = (const float*)d_in[5];
    const float* bhh = (const float*)d_in[6];
    float* out = (float*)d_out;

    unsigned char* ws = (unsigned char*)d_ws;
    unsigned* flags = (unsigned*)ws;                                   // 256 uints
    unsigned short* h1ring = (unsigned short*)(ws + 1024);             // 64 KB
    unsigned short* h2ring = h1ring + 2 * BATCH * HID;                 // 64 KB
    unsigned short* xbf    = h2ring + 2 * BATCH * HID;                 // 32 MB (optional)

    const size_t xbf_need = 1024 + 2 * 128 * 1024 +
                            (size_t)BATCH * T_STEPS * HID * 2 + 4096;
    int use_xbf = (ws_size >= xbf_need) ? 1 : 0;

    hipLaunchKernelGGL(init_flags, dim3(1), dim3(256), 0, stream, flags);

    void* args[] = { (void*)&x, (void*)&h0, (void*)&c0, (void*)&Wih, (void*)&Whh,
                     (void*)&bih, (void*)&bhh, (void*)&out, (void*)&flags,
                     (void*)&h1ring, (void*)&h2ring, (void*)&xbf, (void*)&use_xbf };
    hipError_t e = hipLaunchCooperativeKernel((void*)lstm_persist, dim3(NWG), dim3(256),
                                              args, 0, stream);
    if (e != hipSuccess) {
        hipLaunchKernelGGL(lstm_persist, dim3(NWG), dim3(256), 0, stream,
                           x, h0, c0, Wih, Whh, bih, bhh, out, flags,
                           h1ring, h2ring, xbf, use_xbf);
    }
}

// Round 4
// 7876.379 us; speedup vs baseline: 3.6071x; 1.1079x over previous
//
#include <hip/hip_runtime.h>
#include <math.h>

// Problem constants
#define T_STEPS 1024
#define BATCH   32
#define HID     512
#define G4      2048          // 4*HID
#define KDIM    1024          // I + H (concat [x|h])
#define NWG     128           // total workgroups (64 per layer)
#define WGL     64            // WGs per layer
#define JPW     8             // h-columns owned per WG
#define APAD    1032          // padded row stride (shorts)

#define OUT_ELEMS   (BATCH * T_STEPS * HID)          // 16777216
#define H_OFF       OUT_ELEMS
#define C_OFF       (OUT_ELEMS + 2 * BATCH * HID)

typedef __attribute__((ext_vector_type(8))) short short8;
typedef __attribute__((ext_vector_type(4))) float f32x4;
typedef __attribute__((ext_vector_type(2))) unsigned long long u64x2;

__device__ __forceinline__ unsigned short f2bf(float f) {
    union { float f; unsigned u; } v; v.f = f;
    unsigned r = v.u + 0x7fffu + ((v.u >> 16) & 1u);   // RNE
    return (unsigned short)(r >> 16);
}

__device__ __forceinline__ float sigm(float x)  { return 1.0f / (1.0f + __expf(-x)); }
__device__ __forceinline__ float ftanh(float x) { return 1.0f - 2.0f / (__expf(2.0f * x) + 1.0f); }

// ---- two-level aggregated grid barrier ----
// Data protocol: h rings are written ONLY with sc1 (agent-scope) stores -> never
// dirty in any L2; readers do a per-step agent acquire fence (buffer_inv of
// clean lines) then PLAIN loads -> first toucher per XCD fills L2 from LLC,
// the rest hit local L2. Flags stay agent-scope atomics (LLC-coherent).
__device__ __forceinline__ void g_arrive(unsigned* flags, int wg, unsigned epoch, int tid) {
    asm volatile("s_waitcnt vmcnt(0)" ::: "memory");   // drain sc1 h-publishes
    __syncthreads();
    if (tid == 0)
        __hip_atomic_store(&flags[wg], epoch, __ATOMIC_RELAXED, __HIP_MEMORY_SCOPE_AGENT);
}

__device__ __forceinline__ void g_wait(unsigned* flags, unsigned* rel, int wg, unsigned epoch, int tid) {
    if (wg == 0) {
        if (tid < NWG) {
            while (__hip_atomic_load(&flags[tid], __ATOMIC_RELAXED, __HIP_MEMORY_SCOPE_AGENT) < epoch)
                __builtin_amdgcn_s_sleep(1);
        }
        __syncthreads();
        if (tid == 0)
            __hip_atomic_store(rel, epoch, __ATOMIC_RELAXED, __HIP_MEMORY_SCOPE_AGENT);
    } else {
        if (tid == 0) {
            while (__hip_atomic_load(rel, __ATOMIC_RELAXED, __HIP_MEMORY_SCOPE_AGENT) < epoch)
                __builtin_amdgcn_s_sleep(2);
        }
        __syncthreads();
    }
}

__global__ void init_flags(unsigned* flags) {
    flags[threadIdx.x] = 0u;     // 256 entries: 128 arrival flags + release word + spare
}

__global__ void __launch_bounds__(256, 1)
lstm_persist(const float* __restrict__ x_in,   // [32][1024][512]
             const float* __restrict__ h0,     // [2][32][512]
             const float* __restrict__ c0,     // [2][32][512]
             const float* __restrict__ Wih,    // [2][2048][512]
             const float* __restrict__ Whh,    // [2][2048][512]
             const float* __restrict__ bih,    // [2][2048]
             const float* __restrict__ bhh,    // [2][2048]
             float* __restrict__ out,
             unsigned* __restrict__ flags,
             unsigned short* __restrict__ h1ring,  // [2][32][512] bf16 (ws, sc1-written)
             unsigned short* __restrict__ h2ring,  // [2][32][512] bf16 (ws, sc1-written)
             unsigned short* __restrict__ xbf,     // [32][1024][512] bf16 (ws, plain)
             int use_xbf)
{
    __shared__ __attribute__((aligned(16))) short Abuf[BATCH * APAD];
    __shared__ __attribute__((aligned(16))) short Wbuf[32 * APAD];
    __shared__ float gatebuf[BATCH][33];
    __shared__ float biasbuf[32];

    const int wg    = blockIdx.x;
    const int layer = (wg >= WGL) ? 1 : 0;
    const int wgl   = wg - layer * WGL;
    const int jbase = wgl * JPW;
    const int tid   = threadIdx.x;
    unsigned* rel   = flags + NWG;

    // ---- one-time: pre-convert x -> bf16 in ws (plain stores + release fence) ----
    if (use_xbf) {
        const size_t total4 = (size_t)BATCH * T_STEPS * HID / 4;
        unsigned long long* dst = (unsigned long long*)xbf;
        for (size_t idx = (size_t)wg * 256 + tid; idx < total4; idx += (size_t)NWG * 256) {
            float4 v = *(const float4*)(x_in + idx * 4);
            unsigned long long pk = (unsigned long long)f2bf(v.x)
                                  | ((unsigned long long)f2bf(v.y) << 16)
                                  | ((unsigned long long)f2bf(v.z) << 32)
                                  | ((unsigned long long)f2bf(v.w) << 48);
            dst[idx] = pk;
        }
        __builtin_amdgcn_fence(__ATOMIC_RELEASE, "agent");   // writeback L2 -> LLC
    }

    // ---- one-time: W slice -> LDS (bf16) ----
    {
        const int lr = tid >> 3;        // local gate row 0..31 (= gate*8 + jloc)
        const int g0 = tid & 7;
        const int gg = lr >> 3, jloc = lr & 7;
        const int r  = gg * HID + jbase + jloc;      // global gate row
        const float* srcA = Wih + ((size_t)layer * G4 + r) * HID;
        const float* srcB = Whh + ((size_t)layer * G4 + r) * HID;
        short* dstrow = &Wbuf[lr * APAD];
        #pragma unroll
        for (int i = 0; i < 16; ++i) {
            int g = g0 + 8 * i;         // 16B granule 0..127
            const float* src = (g < 64) ? (srcA + g * 8) : (srcB + (g - 64) * 8);
            float4 v0 = *(const float4*)(src);
            float4 v1 = *(const float4*)(src + 4);
            short8 p;
            p[0] = (short)f2bf(v0.x); p[1] = (short)f2bf(v0.y);
            p[2] = (short)f2bf(v0.z); p[3] = (short)f2bf(v0.w);
            p[4] = (short)f2bf(v1.x); p[5] = (short)f2bf(v1.y);
            p[6] = (short)f2bf(v1.z); p[7] = (short)f2bf(v1.w);
            *(short8*)(dstrow + g * 8) = p;
        }
    }
    if (tid < 32) {
        const int g = tid >> 3, jloc = tid & 7;
        const int r = g * HID + jbase + jloc;
        biasbuf[tid] = bih[(size_t)layer * G4 + r] + bhh[(size_t)layer * G4 + r];
    }

    const int m  = tid >> 3;
    const int jl = tid & 7;
    const int jg = jbase + jl;

    float creg = c0[((size_t)layer * BATCH + m) * HID + jg];

    // init h rings (sc1): readers at step s use slot (s+1)&1
    {
        unsigned hb = (unsigned)f2bf(h0[((size_t)layer * BATCH + m) * HID + jg]);
        unsigned ob = __shfl_xor(hb, 1);
        if ((tid & 1) == 0) {
            unsigned val = hb | (ob << 16);
            unsigned short* ring = (layer == 0) ? h1ring : h2ring;
            if (layer == 0) {
                unsigned* p = (unsigned*)(ring + ((size_t)1 * BATCH + m) * HID + (jg & ~1));
                __hip_atomic_store(p, val, __ATOMIC_RELAXED, __HIP_MEMORY_SCOPE_AGENT);
            } else {
                unsigned* p0 = (unsigned*)(ring + ((size_t)0 * BATCH + m) * HID + (jg & ~1));
                unsigned* p1 = (unsigned*)(ring + ((size_t)1 * BATCH + m) * HID + (jg & ~1));
                __hip_atomic_store(p0, val, __ATOMIC_RELAXED, __HIP_MEMORY_SCOPE_AGENT);
                __hip_atomic_store(p1, val, __ATOMIC_RELAXED, __HIP_MEMORY_SCOPE_AGENT);
            }
        }
    }

    g_arrive(flags, wg, 1u, tid);
    g_wait(flags, rel, wg, 1u, tid);

    const int wv   = tid >> 6;
    const int lane = tid & 63;
    const int mi   = wv & 1;
    const int ni   = wv >> 1;
    const int n16  = lane & 15;
    const int quad = lane >> 4;

    const short* arow = &Abuf[(mi * 16 + n16) * APAD + quad * 8];
    const short* brow = &Wbuf[(ni * 16 + n16) * APAD + quad * 8];

    const int b  = tid >> 3;            // A-build: row, 8 threads/row
    const int g0 = tid & 7;             // starting 16B granule

    for (int s = 0; s <= T_STEPS; ++s) {
        const int t = (layer == 0) ? s : s - 1;
        const bool active = (t >= 0) && (t < T_STEPS);
        float hv = 0.0f;
        if (active) {
            // acquire: invalidate clean L2 lines so plain ring loads see the
            // sc1-written h from the previous step (first touch fills L2/XCD).
            __builtin_amdgcn_fence(__ATOMIC_ACQUIRE, "agent");

            const int rs = (s + 1) & 1;
            short* dstrow = &Abuf[b * APAD];

            if (layer == 0) {
                if (s == 0) {   // x(t=0): not prebuilt yet (plain L2 loads)
                    if (use_xbf) {
                        const unsigned long long* src =
                            (const unsigned long long*)(xbf + ((size_t)b * T_STEPS) * HID);
                        #pragma unroll
                        for (int i = 0; i < 8; ++i) {
                            int g = g0 + 8 * i;
                            *(u64x2*)(dstrow + g * 8) = *(const u64x2*)(src + g * 2);
                        }
                    } else {
                        const float* src = x_in + ((size_t)b * T_STEPS) * HID;
                        #pragma unroll
                        for (int i = 0; i < 8; ++i) {
                            int g = g0 + 8 * i;
                            float4 v0 = *(const float4*)(src + g * 8);
                            float4 v1 = *(const float4*)(src + g * 8 + 4);
                            short8 p;
                            p[0] = (short)f2bf(v0.x); p[1] = (short)f2bf(v0.y);
                            p[2] = (short)f2bf(v0.z); p[3] = (short)f2bf(v0.w);
                            p[4] = (short)f2bf(v1.x); p[5] = (short)f2bf(v1.y);
                            p[6] = (short)f2bf(v1.z); p[7] = (short)f2bf(v1.w);
                            *(short8*)(dstrow + g * 8) = p;
                        }
                    }
                }
            } else {
                // x-part = h1(t): plain loads (L2-cached post-inv)
                const unsigned long long* src =
                    (const unsigned long long*)(h1ring + ((size_t)rs * BATCH + b) * HID);
                #pragma unroll
                for (int i = 0; i < 8; ++i) {
                    int g = g0 + 8 * i;
                    *(u64x2*)(dstrow + g * 8) = *(const u64x2*)(src + g * 2);
                }
            }
            // h-part: cols 512..1023, own layer's recurrence (plain loads)
            {
                const unsigned short* ring = (layer == 0) ? h1ring : h2ring;
                const unsigned long long* src =
                    (const unsigned long long*)(ring + ((size_t)rs * BATCH + b) * HID);
                #pragma unroll
                for (int i = 0; i < 8; ++i) {
                    int g = g0 + 8 * i;
                    *(u64x2*)(dstrow + 512 + g * 8) = *(const u64x2*)(src + g * 2);
                }
            }
            __syncthreads();

            f32x4 acc = {0.f, 0.f, 0.f, 0.f};
            #pragma unroll 16
            for (int k0 = 0; k0 < KDIM; k0 += 32) {
                short8 af = *(const short8*)(arow + k0);
                short8 bf = *(const short8*)(brow + k0);
                acc = __builtin_amdgcn_mfma_f32_16x16x32_bf16(af, bf, acc, 0, 0, 0);
            }
            #pragma unroll
            for (int r = 0; r < 4; ++r)
                gatebuf[mi * 16 + quad * 4 + r][ni * 16 + n16] = acc[r];
            __syncthreads();

            float gi = gatebuf[m][0  + jl] + biasbuf[0  + jl];
            float gf = gatebuf[m][8  + jl] + biasbuf[8  + jl];
            float gg = gatebuf[m][16 + jl] + biasbuf[16 + jl];
            float go = gatebuf[m][24 + jl] + biasbuf[24 + jl];
            float iv = sigm(gi), fv = sigm(gf), gv = ftanh(gg), ov = sigm(go);
            creg = fv * creg + iv * gv;
            hv = ov * ftanh(creg);

            // publish h (sc1, lane-paired u32) — ONLY writer of ring lines
            {
                const int wslot = s & 1;
                unsigned hb = (unsigned)f2bf(hv);
                unsigned ob = __shfl_xor(hb, 1);
                if ((tid & 1) == 0) {
                    unsigned val = hb | (ob << 16);
                    unsigned short* ringw = (layer == 0) ? h1ring : h2ring;
                    unsigned* p = (unsigned*)(ringw + ((size_t)wslot * BATCH + m) * HID + (jg & ~1));
                    __hip_atomic_store(p, val, __ATOMIC_RELAXED, __HIP_MEMORY_SCOPE_AGENT);
                }
            }
            if (t == T_STEPS - 1)
                out[H_OFF + ((size_t)layer * BATCH + m) * HID + jg] = hv;
        }

        const bool last = (s == T_STEPS);
        if (!last) g_arrive(flags, wg, (unsigned)(s + 2), tid);

        // ---- wait-window work (off the critical sync path) ----
        if (active && layer == 1)
            out[((size_t)m * T_STEPS + t) * HID + jg] = hv;     // [B,T,H], plain store
        if (active && layer == 0 && t + 1 < T_STEPS) {
            // prebuild next step's x-part of A -> LDS (immune to next step's inv)
            short* dstrow = &Abuf[b * APAD];
            if (use_xbf) {
                const unsigned long long* src =
                    (const unsigned long long*)(xbf + ((size_t)b * T_STEPS + (t + 1)) * HID);
                #pragma unroll
                for (int i = 0; i < 8; ++i) {
                    int g = g0 + 8 * i;
                    *(u64x2*)(dstrow + g * 8) = *(const u64x2*)(src + g * 2);
                }
            } else {
                const float* src = x_in + ((size_t)b * T_STEPS + (t + 1)) * HID;
                #pragma unroll
                for (int i = 0; i < 8; ++i) {
                    int g = g0 + 8 * i;
                    float4 v0 = *(const float4*)(src + g * 8);
                    float4 v1 = *(const float4*)(src + g * 8 + 4);
                    short8 p;
                    p[0] = (short)f2bf(v0.x); p[1] = (short)f2bf(v0.y);
                    p[2] = (short)f2bf(v0.z); p[3] = (short)f2bf(v0.w);
                    p[4] = (short)f2bf(v1.x); p[5] = (short)f2bf(v1.y);
                    p[6] = (short)f2bf(v1.z); p[7] = (short)f2bf(v1.w);
                    *(short8*)(dstrow + g * 8) = p;
                }
            }
        }
        if (!last) g_wait(flags, rel, wg, (unsigned)(s + 2), tid);
    }

    out[C_OFF + ((size_t)layer * BATCH + m) * HID + jg] = creg;
}

extern "C" void kernel_launch(void* const* d_in, const int* in_sizes, int n_in,
                              void* d_out, int out_size, void* d_ws, size_t ws_size,
                              hipStream_t stream) {
    const float* x   = (const float*)d_in[0];
    const float* h0  = (const float*)d_in[1];
    const float* c0  = (const float*)d_in[2];
    const float* Wih = (const float*)d_in[3];
    const float* Whh = (const float*)d_in[4];
    const float* bih = (const float*)d_in[5];
    const float* bhh = (const float*)d_in[6];
    float* out = (float*)d_out;

    unsigned char* ws = (unsigned char*)d_ws;
    unsigned* flags = (unsigned*)ws;                                   // 256 uints
    unsigned short* h1ring = (unsigned short*)(ws + 1024);             // 64 KB
    unsigned short* h2ring = h1ring + 2 * BATCH * HID;                 // 64 KB
    unsigned short* xbf    = h2ring + 2 * BATCH * HID;                 // 32 MB (optional)

    const size_t xbf_need = 1024 + 2 * 128 * 1024 +
                            (size_t)BATCH * T_STEPS * HID * 2 + 4096;
    int use_xbf = (ws_size >= xbf_need) ? 1 : 0;

    hipLaunchKernelGGL(init_flags, dim3(1), dim3(256), 0, stream, flags);

    void* args[] = { (void*)&x, (void*)&h0, (void*)&c0, (void*)&Wih, (void*)&Whh,
                     (void*)&bih, (void*)&bhh, (void*)&out, (void*)&flags,
                     (void*)&h1ring, (void*)&h2ring, (void*)&xbf, (void*)&use_xbf };
    hipError_t e = hipLaunchCooperativeKernel((void*)lstm_persist, dim3(NWG), dim3(256),
                                              args, 0, stream);
    if (e != hipSuccess) {
        hipLaunchKernelGGL(lstm_persist, dim3(NWG), dim3(256), 0, stream,
                           x, h0, c0, Wih, Whh, bih, bhh, out, flags,
                           h1ring, h2ring, xbf, use_xbf);
    }
}